// Round 13
// baseline (263.711 us; speedup 1.0000x reference)
//
#include <hip/hip_runtime.h>
#include <math.h>

// Greedy farthest-point selection via precomputed Gram matrix.
// kgram3s: 128x128-tile MFMA Gram (f16 2-way split, 3 products, f32 accum),
//          SINGLE-buffer LDS (40KB -> 4 blocks/CU, all 768 blocks resident;
//          stall coverage via cross-block wave overlap per m114), 2 barriers
//          per chunk, reg-prefetch next chunk. Square G output (stride 304).
// ksel_sq: greedy argmin (1 wave/batch), sorted idx -> ws.
// kgath  : gather, 2 blocks/batch (R12 bug was here: audio half = 1024 f4,
//          not 512 — rows k>=32 were never written).
// Fallbacks: tri-G R9 path (ws >= 23.1 MB), then 3-kernel split path.

constexpr int BB = 128, NN = 300, DV = 1024, DA = 128, KK = 64;
constexpr int TRI = NN * (NN + 1) / 2;        // 45150
constexpr int KC = 32;
constexpr int NCH = DV / KC;                  // 32 chunks
constexpr int LDH = 36;                       // f16 row stride: 72 B

// square-G geometry
constexpr int GS = 304;
constexpr int GBATCH = NN * GS;               // 91200 floats/batch
constexpr size_t SQ_BYTES = (size_t)BB * GBATCH * 4;    // 46.7 MB
constexpr size_t IDX_OFF  = SQ_BYTES;
constexpr size_t SQ_NEED  = SQ_BYTES + (size_t)BB * KK * 4;

constexpr int NT2 = 6;
__device__ __constant__ int t2_ib[NT2] = {0,0,0,1,1,2};
__device__ __constant__ int t2_jb[NT2] = {0,1,2,1,2,2};

constexpr int NTILES = 15;
constexpr int TB = 64;
__device__ __constant__ int c_ib[NTILES] = {0,0,0,0,0, 1,1,1,1, 2,2,2, 3,3, 4};
__device__ __constant__ int c_jb[NTILES] = {0,1,2,3,4, 1,2,3,4, 2,3,4, 3,4, 4};

typedef _Float16 f16x8 __attribute__((ext_vector_type(8)));
typedef float    f32x4 __attribute__((ext_vector_type(4)));

union H4 { _Float16 h[4]; uint2 u; };
union F8 { uint2 u2[2]; f16x8 v; };

__device__ __forceinline__ int tri_base(int i) { return i * NN - (i * (i - 1)) / 2; }

// ---------------- 1a. kgram3s: 128-tile, single-buffer, square-G ----------
__global__ __launch_bounds__(512, 4) void kgram3s(const float* __restrict__ video,
                                                  float* __restrict__ G) {
    const int bid  = blockIdx.x;
    const int swz  = (bid & 7) * 96 + (bid >> 3);       // bijective: 768=8*96
    const int batch = swz / NT2;
    const int tile  = swz - batch * NT2;
    const int i0 = t2_ib[tile] * 128, j0 = t2_jb[tile] * 128;
    const bool diag = (i0 == j0);
    const int tid = threadIdx.x;

    __shared__ _Float16 sH[4][128][LDH];   // [A-hi,A-lo,B-hi,B-lo] 36.9 KB
    __shared__ float    s_part[512];
    __shared__ double   s_inv[2][128];

    const float* vb = video + (size_t)batch * NN * DV;

    // staging role: 2 threads per row (khalf), 256 rows (A128 + B128)
    const int slab  = tid >> 8;
    const int st    = tid & 255;
    const int lrow  = st >> 1;
    const int khalf = st & 1;
    const int grow  = (slab ? j0 : i0) + lrow;
    const bool rok  = grow < NN;
    const bool stage_on = !(diag && slab == 1);
    const float4* srcb4 = (const float4*)(vb + (size_t)(rok ? grow : 0) * DV);
    const int qbase = khalf * 4;

    // compute role
    const int lane = tid & 63, w = tid >> 6;
    const int wr2 = w >> 2, wc2 = w & 3;
    const int g = lane >> 4, c16 = lane & 15;
    const int bplane = diag ? 0 : 2;

    f32x4 acc[4][2];
    #pragma unroll
    for (int fr = 0; fr < 4; ++fr)
        #pragma unroll
        for (int fc = 0; fc < 2; ++fc) acc[fr][fc] = (f32x4){0.f, 0.f, 0.f, 0.f};

    float ps = 0.f;
    float4 ld[4];
    const float4 z4 = make_float4(0.f, 0.f, 0.f, 0.f);

    auto stage_write = [&]() {
        #pragma unroll
        for (int q = 0; q < 4; ++q) {
            float4 v = ld[q];
            ps = fmaf(v.x, v.x, fmaf(v.y, v.y, fmaf(v.z, v.z, fmaf(v.w, v.w, ps))));
            H4 hi, lo;
            _Float16 h0 = (_Float16)v.x, h1 = (_Float16)v.y,
                     h2 = (_Float16)v.z, h3 = (_Float16)v.w;
            hi.h[0] = h0; hi.h[1] = h1; hi.h[2] = h2; hi.h[3] = h3;
            lo.h[0] = (_Float16)(v.x - (float)h0);
            lo.h[1] = (_Float16)(v.y - (float)h1);
            lo.h[2] = (_Float16)(v.z - (float)h2);
            lo.h[3] = (_Float16)(v.w - (float)h3);
            const int p = khalf * 16 + 4 * q;
            *(uint2*)&sH[slab * 2 + 0][lrow][p] = hi.u;
            *(uint2*)&sH[slab * 2 + 1][lrow][p] = lo.u;
        }
    };

    // prologue: chunk 0 into regs
    if (stage_on) {
        #pragma unroll
        for (int q = 0; q < 4; ++q) ld[q] = rok ? srcb4[qbase + q] : z4;
    }

    for (int kc = 0; kc < NCH; ++kc) {
        if (stage_on) {
            stage_write();                       // stage chunk kc
            if (kc < NCH - 1) {                  // prefetch chunk kc+1
                #pragma unroll
                for (int q = 0; q < 4; ++q)
                    ld[q] = rok ? srcb4[(kc + 1) * 8 + qbase + q] : z4;
            }
        }
        __syncthreads();                         // staging visible

        f16x8 Ah[4], Al[4], Bh[2], Bl[2];
        #pragma unroll
        for (int fr = 0; fr < 4; ++fr) {
            const int row = 64 * wr2 + 16 * fr + c16;
            F8 t;
            t.u2[0] = *(const uint2*)&sH[0][row][4 * g];
            t.u2[1] = *(const uint2*)&sH[0][row][16 + 4 * g];
            Ah[fr] = t.v;
            t.u2[0] = *(const uint2*)&sH[1][row][4 * g];
            t.u2[1] = *(const uint2*)&sH[1][row][16 + 4 * g];
            Al[fr] = t.v;
        }
        #pragma unroll
        for (int fc = 0; fc < 2; ++fc) {
            const int row = 32 * wc2 + 16 * fc + c16;
            F8 t;
            t.u2[0] = *(const uint2*)&sH[bplane + 0][row][4 * g];
            t.u2[1] = *(const uint2*)&sH[bplane + 0][row][16 + 4 * g];
            Bh[fc] = t.v;
            t.u2[0] = *(const uint2*)&sH[bplane + 1][row][4 * g];
            t.u2[1] = *(const uint2*)&sH[bplane + 1][row][16 + 4 * g];
            Bl[fc] = t.v;
        }
        #pragma unroll
        for (int fr = 0; fr < 4; ++fr)
            #pragma unroll
            for (int fc = 0; fc < 2; ++fc) {
                acc[fr][fc] = __builtin_amdgcn_mfma_f32_16x16x32_f16(Ah[fr], Bh[fc], acc[fr][fc], 0, 0, 0);
                acc[fr][fc] = __builtin_amdgcn_mfma_f32_16x16x32_f16(Ah[fr], Bl[fc], acc[fr][fc], 0, 0, 0);
                acc[fr][fc] = __builtin_amdgcn_mfma_f32_16x16x32_f16(Al[fr], Bh[fc], acc[fr][fc], 0, 0, 0);
            }
        __syncthreads();                         // compute done before restage
    }

    // ---- norms ----
    s_part[tid] = ps;
    __syncthreads();
    if (tid < 256) {
        const int sl = tid >> 7, r = tid & 127;
        const int src = (sl && !diag) ? 256 + 2 * r : 2 * r;
        float ssum = s_part[src] + s_part[src + 1];
        s_inv[sl][r] = 1.0 / (sqrt((double)ssum) + 1e-5);
    }
    __syncthreads();

    float* Gb = G + (size_t)batch * GBATCH;
    #pragma unroll
    for (int fr = 0; fr < 4; ++fr)
        #pragma unroll
        for (int fc = 0; fc < 2; ++fc)
            #pragma unroll
            for (int reg = 0; reg < 4; ++reg) {
                const int il = 64 * wr2 + 16 * fr + 4 * g + reg;  // D row (m89)
                const int jl = 32 * wc2 + 16 * fc + c16;          // D col (m89)
                const int i = i0 + il, j = j0 + jl;
                if (i <= j && j < NN) {
                    float val = (float)(fabs((double)acc[fr][fc][reg]) *
                                        s_inv[0][il] * s_inv[1][jl]);
                    Gb[i * GS + j] = val;
                    Gb[j * GS + i] = val;
                }
            }
}

// ---------------- 1b. fallback: R9 64-tile tri-G kgram ----------------
__global__ __launch_bounds__(256) void kgram_lds(const float* __restrict__ video,
                                                 float* __restrict__ G) {
    const int bid  = blockIdx.x;
    const int swz  = (bid & 7) * 240 + (bid >> 3);
    const int batch = swz / 15;
    const int tile  = swz - batch * 15;
    const int i0 = c_ib[tile] * TB, j0 = c_jb[tile] * TB;
    const bool diag = (i0 == j0);
    const int tid = threadIdx.x;

    __shared__ _Float16 sH[2][4][TB][LDH];
    __shared__ float    s_part[256];
    __shared__ double   s_inv[2][TB];

    const float* vb = video + (size_t)batch * NN * DV;

    const int slab  = tid >> 7;
    const int lrow  = (tid >> 1) & 63;
    const int khalf = tid & 1;
    const int grow  = (slab ? j0 : i0) + lrow;
    const bool rok  = grow < NN;
    const bool stage_on = !(diag && slab == 1);
    const float4* srcb4 = (const float4*)(vb + (size_t)(rok ? grow : 0) * DV);
    const int qbase = khalf * 4;

    const int lane = tid & 63, w = tid >> 6;
    const int wr = w >> 1, wc = w & 1;
    const int g = lane >> 4, c16 = lane & 15;
    const int bplane = diag ? 0 : 2;

    f32x4 acc[2][2];
    #pragma unroll
    for (int fr = 0; fr < 2; ++fr)
        #pragma unroll
        for (int fc = 0; fc < 2; ++fc) acc[fr][fc] = (f32x4){0.f, 0.f, 0.f, 0.f};

    float ps = 0.f;
    float4 ld[4];
    const float4 z4 = make_float4(0.f, 0.f, 0.f, 0.f);

    auto stage_write = [&](int bf) {
        #pragma unroll
        for (int q = 0; q < 4; ++q) {
            float4 v = ld[q];
            ps = fmaf(v.x, v.x, fmaf(v.y, v.y, fmaf(v.z, v.z, fmaf(v.w, v.w, ps))));
            H4 hi, lo;
            _Float16 h0 = (_Float16)v.x, h1 = (_Float16)v.y,
                     h2 = (_Float16)v.z, h3 = (_Float16)v.w;
            hi.h[0] = h0; hi.h[1] = h1; hi.h[2] = h2; hi.h[3] = h3;
            lo.h[0] = (_Float16)(v.x - (float)h0);
            lo.h[1] = (_Float16)(v.y - (float)h1);
            lo.h[2] = (_Float16)(v.z - (float)h2);
            lo.h[3] = (_Float16)(v.w - (float)h3);
            const int p = khalf * 16 + 4 * q;
            *(uint2*)&sH[bf][slab * 2 + 0][lrow][p] = hi.u;
            *(uint2*)&sH[bf][slab * 2 + 1][lrow][p] = lo.u;
        }
    };

    if (stage_on) {
        #pragma unroll
        for (int q = 0; q < 4; ++q) ld[q] = rok ? srcb4[qbase + q] : z4;
        stage_write(0);
        #pragma unroll
        for (int q = 0; q < 4; ++q) ld[q] = rok ? srcb4[8 + qbase + q] : z4;
    }
    __syncthreads();

    for (int kc = 0; kc < NCH; ++kc) {
        const int cur = kc & 1, nxt = cur ^ 1;
        if (stage_on && kc < NCH - 1) stage_write(nxt);
        if (stage_on && kc < NCH - 2) {
            #pragma unroll
            for (int q = 0; q < 4; ++q)
                ld[q] = rok ? srcb4[(kc + 2) * 8 + qbase + q] : z4;
        }

        f16x8 Ah[2], Al[2], Bh[2], Bl[2];
        #pragma unroll
        for (int fr = 0; fr < 2; ++fr) {
            const int row = 32 * wr + 16 * fr + c16;
            F8 t;
            t.u2[0] = *(const uint2*)&sH[cur][0][row][4 * g];
            t.u2[1] = *(const uint2*)&sH[cur][0][row][16 + 4 * g];
            Ah[fr] = t.v;
            t.u2[0] = *(const uint2*)&sH[cur][1][row][4 * g];
            t.u2[1] = *(const uint2*)&sH[cur][1][row][16 + 4 * g];
            Al[fr] = t.v;
        }
        #pragma unroll
        for (int fc = 0; fc < 2; ++fc) {
            const int row = 32 * wc + 16 * fc + c16;
            F8 t;
            t.u2[0] = *(const uint2*)&sH[cur][bplane + 0][row][4 * g];
            t.u2[1] = *(const uint2*)&sH[cur][bplane + 0][row][16 + 4 * g];
            Bh[fc] = t.v;
            t.u2[0] = *(const uint2*)&sH[cur][bplane + 1][row][4 * g];
            t.u2[1] = *(const uint2*)&sH[cur][bplane + 1][row][16 + 4 * g];
            Bl[fc] = t.v;
        }
        #pragma unroll
        for (int fr = 0; fr < 2; ++fr)
            #pragma unroll
            for (int fc = 0; fc < 2; ++fc) {
                acc[fr][fc] = __builtin_amdgcn_mfma_f32_16x16x32_f16(Ah[fr], Bh[fc], acc[fr][fc], 0, 0, 0);
                acc[fr][fc] = __builtin_amdgcn_mfma_f32_16x16x32_f16(Ah[fr], Bl[fc], acc[fr][fc], 0, 0, 0);
                acc[fr][fc] = __builtin_amdgcn_mfma_f32_16x16x32_f16(Al[fr], Bh[fc], acc[fr][fc], 0, 0, 0);
            }
        __syncthreads();
    }

    s_part[tid] = ps;
    __syncthreads();
    if (tid < 128) {
        const int sl = tid >> 6, r = tid & 63;
        const int src = (sl && !diag) ? 128 + 2 * r : 2 * r;
        float ssum = s_part[src] + s_part[src + 1];
        s_inv[sl][r] = 1.0 / (sqrt((double)ssum) + 1e-5);
    }
    __syncthreads();

    float* Gb = G + (size_t)batch * TRI;
    #pragma unroll
    for (int fr = 0; fr < 2; ++fr)
        #pragma unroll
        for (int fc = 0; fc < 2; ++fc)
            #pragma unroll
            for (int reg = 0; reg < 4; ++reg) {
                const int il = 32 * wr + 16 * fr + 4 * g + reg;
                const int jl = 32 * wc + 16 * fc + c16;
                const int i = i0 + il, j = j0 + jl;
                if (i <= j && j < NN)
                    Gb[tri_base(i) + (j - i)] =
                        (float)(fabs((double)acc[fr][fc][reg]) * s_inv[0][il] * s_inv[1][jl]);
            }
}

// ---- selection helpers ----
__device__ __forceinline__ void select_wave_sq(const float* __restrict__ Gb,
                                               int lane, int* s_sorted) {
    float best[5];
    int myidx = 0;

    #pragma unroll
    for (int q = 0; q < 5; ++q) {
        int r = lane + 64 * q;
        best[q] = (r < NN) ? Gb[r] : 3.4e38f;
    }

    int last;
    {
        float v = INFINITY; int ri = 1 << 30;
        #pragma unroll
        for (int q = 0; q < 5; ++q)
            if (best[q] < v) { v = best[q]; ri = lane + 64 * q; }
        #pragma unroll
        for (int off = 32; off >= 1; off >>= 1) {
            float ov = __shfl_xor(v, off, 64); int oi = __shfl_xor(ri, off, 64);
            if (ov < v || (ov == v && oi < ri)) { v = ov; ri = oi; }
        }
        last = ri;
    }
    if (lane == 1) myidx = last;

    for (int t = 2; t < KK; ++t) {
        const float* row = Gb + last * GS;
        #pragma unroll
        for (int q = 0; q < 5; ++q) {
            int r = lane + 64 * q;
            if (r < NN) best[q] = fmaxf(best[q], row[r]);
        }
        float v = INFINITY; int ri = 1 << 30;
        #pragma unroll
        for (int q = 0; q < 5; ++q)
            if (best[q] < v) { v = best[q]; ri = lane + 64 * q; }
        #pragma unroll
        for (int off = 32; off >= 1; off >>= 1) {
            float ov = __shfl_xor(v, off, 64); int oi = __shfl_xor(ri, off, 64);
            if (ov < v || (ov == v && oi < ri)) { v = ov; ri = oi; }
        }
        last = ri;
        if (lane == t) myidx = last;
    }

    int rank = 0;
    for (int j = 0; j < KK; ++j) {
        int oj = __shfl(myidx, j, 64);
        rank += (oj < myidx) || (oj == myidx && j < lane);
    }
    s_sorted[rank] = myidx;
}

__device__ __forceinline__ void select_wave_tri(const float* __restrict__ Gb,
                                                int lane, int* s_sorted) {
    float best[5];
    int myidx = 0;

    #pragma unroll
    for (int q = 0; q < 5; ++q) {
        int r = lane + 64 * q;
        best[q] = (r < NN) ? Gb[r] : 3.4e38f;
    }

    int last;
    {
        float v = INFINITY; int ri = 1 << 30;
        #pragma unroll
        for (int q = 0; q < 5; ++q)
            if (best[q] < v) { v = best[q]; ri = lane + 64 * q; }
        #pragma unroll
        for (int off = 32; off >= 1; off >>= 1) {
            float ov = __shfl_xor(v, off, 64); int oi = __shfl_xor(ri, off, 64);
            if (ov < v || (ov == v && oi < ri)) { v = ov; ri = oi; }
        }
        last = ri;
    }
    if (lane == 1) myidx = last;

    for (int t = 2; t < KK; ++t) {
        #pragma unroll
        for (int q = 0; q < 5; ++q) {
            int r = lane + 64 * q;
            if (r < NN) {
                int i = min(last, r), j = max(last, r);
                best[q] = fmaxf(best[q], Gb[tri_base(i) + (j - i)]);
            }
        }
        float v = INFINITY; int ri = 1 << 30;
        #pragma unroll
        for (int q = 0; q < 5; ++q)
            if (best[q] < v) { v = best[q]; ri = lane + 64 * q; }
        #pragma unroll
        for (int off = 32; off >= 1; off >>= 1) {
            float ov = __shfl_xor(v, off, 64); int oi = __shfl_xor(ri, off, 64);
            if (ov < v || (ov == v && oi < ri)) { v = ov; ri = oi; }
        }
        last = ri;
        if (lane == t) myidx = last;
    }

    int rank = 0;
    for (int j = 0; j < KK; ++j) {
        int oj = __shfl(myidx, j, 64);
        rank += (oj < myidx) || (oj == myidx && j < lane);
    }
    s_sorted[rank] = myidx;
}

// ---------------- 2a. selection -> idx in ws ----------------
__global__ __launch_bounds__(64) void ksel_sq(const float* __restrict__ G,
                                              int* __restrict__ idx) {
    __shared__ int s_sorted[KK];
    select_wave_sq(G + (size_t)blockIdx.x * GBATCH, threadIdx.x, s_sorted);
    __syncthreads();
    idx[blockIdx.x * KK + threadIdx.x] = s_sorted[threadIdx.x];
}

// ---------------- 2b. gather, 2 blocks per batch ----------------
__global__ __launch_bounds__(256) void kgath(const int* __restrict__ idx,
                                             const float* __restrict__ video,
                                             const float* __restrict__ audio,
                                             float* __restrict__ out_v,
                                             float* __restrict__ out_a) {
    const int b = blockIdx.x >> 1, half = blockIdx.x & 1, tid = threadIdx.x;
    __shared__ int s_idx[KK];
    if (tid < KK) s_idx[tid] = idx[b * KK + tid];
    __syncthreads();

    const float4* vb4 = (const float4*)(video + (size_t)b * NN * DV);
    float4* ov4 = (float4*)(out_v + (size_t)b * KK * DV);
    const int vbeg = half * 8192, vend = vbeg + 8192;       // KK*DV/4 = 16384
    #pragma unroll 4
    for (int t = vbeg + tid; t < vend; t += 256) {
        int k = t >> 8, c = t & 255;
        ov4[t] = vb4[s_idx[k] * (DV / 4) + c];
    }
    const float4* ab4 = (const float4*)(audio + (size_t)b * NN * DA);
    float4* oa4 = (float4*)(out_a + (size_t)b * KK * DA);
    const int abeg = half * 1024, aend = abeg + 1024;       // KK*DA/4 = 2048
    for (int t = abeg + tid; t < aend; t += 256) {
        int k = t >> 5, c = t & 31;
        oa4[t] = ab4[s_idx[k] * (DA / 4) + c];
    }
}

// ---------------- fallback fused / split kernels ----------------
__global__ __launch_bounds__(256) void kfused_tri(const float* __restrict__ G,
                                                  const float* __restrict__ video,
                                                  const float* __restrict__ audio,
                                                  float* __restrict__ out_v,
                                                  float* __restrict__ out_a) {
    const int b = blockIdx.x, tid = threadIdx.x;
    __shared__ int s_sorted[KK];

    if (tid < 64)
        select_wave_tri(G + (size_t)b * TRI, tid, s_sorted);
    __syncthreads();

    const float4* vb4 = (const float4*)(video + (size_t)b * NN * DV);
    float4* ov4 = (float4*)(out_v + (size_t)b * KK * DV);
    #pragma unroll 4
    for (int t = tid; t < KK * DV / 4; t += 256) {
        int k = t >> 8, c = t & 255;
        ov4[t] = vb4[s_sorted[k] * (DV / 4) + c];
    }
    const float4* ab4 = (const float4*)(audio + (size_t)b * NN * DA);
    float4* oa4 = (float4*)(out_a + (size_t)b * KK * DA);
    for (int t = tid; t < KK * DA / 4; t += 256) {
        int k = t >> 5, c = t & 31;
        oa4[t] = ab4[s_sorted[k] * (DA / 4) + c];
    }
}

__global__ __launch_bounds__(64) void kselect(const float* __restrict__ G,
                                              float* __restrict__ out_a) {
    __shared__ int s_sorted[KK];
    select_wave_tri(G + (size_t)blockIdx.x * TRI, threadIdx.x, s_sorted);
    __syncthreads();
    ((int*)(out_a + (size_t)blockIdx.x * KK * DA))[threadIdx.x] = s_sorted[threadIdx.x];
}

__global__ __launch_bounds__(256) void kgather(const float* __restrict__ video,
                                               const float* __restrict__ audio,
                                               float* __restrict__ out_v,
                                               float* __restrict__ out_a) {
    int b = blockIdx.x, tid = threadIdx.x;
    __shared__ int s_idx[KK];
    const int* idxp = (const int*)(out_a + (size_t)b * KK * DA);
    if (tid < KK) s_idx[tid] = idxp[tid];
    __syncthreads();

    const float4* vb4 = (const float4*)(video + (size_t)b * NN * DV);
    float4* ov4 = (float4*)(out_v + (size_t)b * KK * DV);
    #pragma unroll 4
    for (int t = tid; t < KK * DV / 4; t += 256) {
        int k = t >> 8, c = t & 255;
        ov4[t] = vb4[s_idx[k] * (DV / 4) + c];
    }
    const float4* ab4 = (const float4*)(audio + (size_t)b * NN * DA);
    float4* oa4 = (float4*)(out_a + (size_t)b * KK * DA);
    for (int t = tid; t < KK * DA / 4; t += 256) {
        int k = t >> 5, c = t & 31;
        oa4[t] = ab4[s_idx[k] * (DA / 4) + c];
    }
}

extern "C" void kernel_launch(void* const* d_in, const int* in_sizes, int n_in,
                              void* d_out, int out_size, void* d_ws, size_t ws_size,
                              hipStream_t stream) {
    const float* video = (const float*)d_in[0];
    const float* audio = (const float*)d_in[1];
    float* out   = (float*)d_out;
    float* out_v = out;
    float* out_a = out + (size_t)BB * KK * DV;

    const size_t tri_bytes = (size_t)BB * TRI * sizeof(float);   // 23.1 MB

    if (ws_size >= SQ_NEED) {
        float* G = (float*)d_ws;
        int* idx = (int*)((char*)d_ws + IDX_OFF);
        kgram3s<<<NT2 * BB, 512, 0, stream>>>(video, G);
        ksel_sq<<<BB, 64, 0, stream>>>(G, idx);
        kgath  <<<2 * BB, 256, 0, stream>>>(idx, video, audio, out_v, out_a);
    } else if (ws_size >= tri_bytes) {
        float* G = (float*)d_ws;
        kgram_lds <<<NTILES * BB, 256, 0, stream>>>(video, G);
        kfused_tri<<<BB, 256, 0, stream>>>(G, video, audio, out_v, out_a);
    } else {
        float* G = out;
        kgram_lds<<<NTILES * BB, 256, 0, stream>>>(video, G);
        kselect  <<<BB, 64, 0, stream>>>(G, out_a);
        kgather  <<<BB, 256, 0, stream>>>(video, audio, out_v, out_a);
    }
}